// Round 6
// baseline (142.451 us; speedup 1.0000x reference)
//
#include <hip/hip_runtime.h>
#include <hip/hip_bf16.h>

// out[b] = SCALE * query[b] @ P[b] + row[b]
//   P[b] = Wq^T @ N[b],  N[b] = Kz[b]^T @ M,  Kz = mask*(key@Wk^T + bk)
//   M = Wc1^T + prev @ Wc2^T
//   row[b][d] = bc[d] - 1e9*sum_{masked k} M[k][d] + SCALE*(bq@N[b])[d]
// NT GEMMs, bf16 MFMA 16x16x32, BK=64, global_load_lds(16B),
// rotation LDS swizzle g'=(g+row)&7 (measured 0 conflicts), bijective XCD
// swizzle, T3-minimum 2-phase double-buffered prefetch pipeline:
//   stage(buf0); sync; loop{ stage(buf^1,next); compute(buf); sync; } compute.
// Mask-constant path fp32 (Mt_f / k_row).

typedef __attribute__((ext_vector_type(8))) short short8;
typedef __attribute__((ext_vector_type(4))) float f32x4;

#define SCALE 0.03608439182435161f   /* 1/sqrt(768) */

__device__ inline unsigned short f2bf(float x) {
  unsigned int u = __builtin_bit_cast(unsigned int, x);
  u = (u + 0x7fffu + ((u >> 16) & 1u)) >> 16;   // RNE
  return (unsigned short)u;
}
__device__ inline float bf2f(unsigned short h) {
  return __builtin_bit_cast(float, ((unsigned int)h) << 16);
}

// ---------------- prep kernels ----------------
__global__ void k_cvt(const float* __restrict__ s, unsigned short* __restrict__ d, int n4) {
  int i = blockIdx.x * 256 + threadIdx.x;
  if (i >= n4) return;
  float4 v = reinterpret_cast<const float4*>(s)[i];
  reinterpret_cast<ushort4*>(d)[i] = make_ushort4(f2bf(v.x), f2bf(v.y), f2bf(v.z), f2bf(v.w));
}

// merged small preps: region 0 = Wk cvt, 1 = prev cvt, 2 = Wc2 slice cvt
__global__ void k_prep(const float* __restrict__ Wk, const float* __restrict__ prev,
                       const float* __restrict__ Wc,
                       unsigned short* __restrict__ Wk_bf,
                       unsigned short* __restrict__ prev_bf,
                       unsigned short* __restrict__ Wc2_bf) {
  int g = blockIdx.x;
  int region = g / 576;
  int idx = (g - region * 576) * 256 + threadIdx.x;       // < 147456 float4-groups
  float4 v;
  unsigned short* dst;
  if (region == 0)      { v = reinterpret_cast<const float4*>(Wk)[idx];   dst = Wk_bf; }
  else if (region == 1) { v = reinterpret_cast<const float4*>(prev)[idx]; dst = prev_bf; }
  else {
    int r = idx / 192, c4 = (idx - r * 192) * 4;
    v = *reinterpret_cast<const float4*>(Wc + (long long)r * 1536 + 768 + c4);
    dst = Wc2_bf;
  }
  reinterpret_cast<ushort4*>(dst)[idx] = make_ushort4(f2bf(v.x), f2bf(v.y), f2bf(v.z), f2bf(v.w));
}

// WqT[d0][d1] = Wq[d1][d0] -> bf16, LDS-tiled coalesced transpose
__global__ void k_transpose(const float* __restrict__ src, unsigned short* __restrict__ dst) {
  __shared__ float t[64][65];
  int bx = blockIdx.x * 64, by = blockIdx.y * 64;
  int tx = threadIdx.x & 63, ty = threadIdx.x >> 6;
  #pragma unroll
  for (int i = 0; i < 64; i += 4)
    t[ty + i][tx] = src[(long long)(by + ty + i) * 768 + bx + tx];
  __syncthreads();
  #pragma unroll
  for (int i = 0; i < 64; i += 4)
    dst[(long long)(bx + ty + i) * 768 + by + tx] = f2bf(t[tx][ty + i]);
}

// ---------------- NT GEMM: C[m][n] = sum_k A[m][k]*B[n][k], K=768, BK=64 ----------
// MODE 0: Mt fp32+bf16 = acc + Wc1[m][n] (aux=Wc ld1536)
// MODE 1: KzT bf16 = mask[b][n] ? acc + bk[m] : 0
// MODE 2/3: bf16 = acc
// MODE 4: out fp32 = SCALE*acc + row[b][n]
template <int MODE, int BM, int BN>
__global__ __launch_bounds__(256) void gemm_nt(
    const unsigned short* __restrict__ A, long long aStr, int lda,
    const unsigned short* __restrict__ B, long long bStr, int ldb,
    float* __restrict__ Cf, unsigned short* __restrict__ Cbf,
    long long cStr, int ldc,
    const float* __restrict__ aux, const int* __restrict__ mask)
{
  constexpr int BK = 64;                   // 128B rows = 8 granules of 16B
  constexpr int MI = BM / 32;              // per-wave fragments (2x2 wave grid)
  constexpr int NJ = BN / 32;
  constexpr int AGT = BM * 8 / 256;        // gload iters per tile (A)
  constexpr int BGT = BN * 8 / 256;
  constexpr int ASZ = BM * BK * 2, BSZ = BN * BK * 2;
  __shared__ __align__(16) char As[2 * ASZ];
  __shared__ __align__(16) char Bs[2 * BSZ];

  // bijective XCD swizzle (m204): one contiguous logical chunk per XCD
  const int gx = gridDim.x, gy = gridDim.y;
  const int nwg = gx * gy * (int)gridDim.z;
  int lin = blockIdx.x + gx * (blockIdx.y + gy * blockIdx.z);
  int qq = nwg >> 3, rr = nwg & 7, xcd = lin & 7, loc = lin >> 3;
  int swz = (xcd < rr ? xcd * (qq + 1) : rr * (qq + 1) + (xcd - rr) * qq) + loc;
  int bz = swz / (gx * gy);
  int rem = swz - bz * gx * gy;
  int by = rem / gx, bx = rem - by * gx;

  const int b = bz;
  const unsigned short* Ab = A + (long long)b * aStr;
  const unsigned short* Bb = B + (long long)b * bStr;
  const int m0 = by * BM, n0 = bx * BN;

  const int tid = threadIdx.x;
  const int w = tid >> 6, lane = tid & 63;
  const int wr = w >> 1, wc = w & 1;       // 2x2 waves
  const int fr = lane & 15, fq = lane >> 4;

  f32x4 acc[MI][NJ] = {};

  // stage tile at kt into buffer buf: linear LDS dest, inverse-rotated source (rule 21)
  auto stage = [&](int buf, int kt) {
    char* ad = As + buf * ASZ;
    char* bd = Bs + buf * BSZ;
    #pragma unroll
    for (int t = 0; t < AGT; ++t) {
      int g = t * 256 + tid;
      int row = g >> 3, s = g & 7;
      int sg = (s - row) & 7;
      const unsigned short* ga = Ab + (long long)(m0 + row) * lda + kt + sg * 8;
      __builtin_amdgcn_global_load_lds(
          (const __attribute__((address_space(1))) void*)ga,
          (__attribute__((address_space(3))) void*)(ad + g * 16), 16, 0, 0);
    }
    #pragma unroll
    for (int t = 0; t < BGT; ++t) {
      int g = t * 256 + tid;
      int row = g >> 3, s = g & 7;
      int sg = (s - row) & 7;
      const unsigned short* gb = Bb + (long long)(n0 + row) * ldb + kt + sg * 8;
      __builtin_amdgcn_global_load_lds(
          (const __attribute__((address_space(1))) void*)gb,
          (__attribute__((address_space(3))) void*)(bd + g * 16), 16, 0, 0);
    }
  };

  auto compute = [&](int buf) {
    const char* as = As + buf * ASZ;
    const char* bs = Bs + buf * BSZ;
    #pragma unroll
    for (int kk = 0; kk < 2; ++kk) {
      short8 af[MI], bfr[NJ];
      #pragma unroll
      for (int i = 0; i < MI; ++i) {
        int r = wr * (BM / 2) + i * 16 + fr;
        int sgi = ((kk * 4 + fq) + r) & 7;          // rotation-swizzled granule
        af[i] = *reinterpret_cast<const short8*>(as + r * 128 + sgi * 16);
      }
      #pragma unroll
      for (int j = 0; j < NJ; ++j) {
        int r = wc * (BN / 2) + j * 16 + fr;
        int sgj = ((kk * 4 + fq) + r) & 7;
        bfr[j] = *reinterpret_cast<const short8*>(bs + r * 128 + sgj * 16);
      }
      #pragma unroll
      for (int i = 0; i < MI; ++i)
        #pragma unroll
        for (int j = 0; j < NJ; ++j)
          acc[i][j] = __builtin_amdgcn_mfma_f32_16x16x32_bf16(af[i], bfr[j], acc[i][j], 0, 0, 0);
    }
  };

  // T3-minimum 2-phase pipeline: loads for tile t+1 fly during compute of tile t;
  // the single __syncthreads (compiler drains vmcnt+lgkmcnt) lands AFTER compute.
  stage(0, 0);
  __syncthreads();
  int cur = 0;
  for (int kt = BK; kt < 768; kt += BK) {
    stage(cur ^ 1, kt);
    compute(cur);
    __syncthreads();
    cur ^= 1;
  }
  compute(cur);

  const int* mb = (MODE == 1) ? (mask + b * 768) : nullptr;
  #pragma unroll
  for (int i = 0; i < MI; ++i)
    #pragma unroll
    for (int j = 0; j < NJ; ++j)
      #pragma unroll
      for (int r = 0; r < 4; ++r) {
        int row = m0 + wr * (BM / 2) + i * 16 + fq * 4 + r;  // C/D: col=lane&15, row=(lane>>4)*4+r
        int col = n0 + wc * (BN / 2) + j * 16 + fr;
        float v = acc[i][j][r];
        if constexpr (MODE == 0) {
          v += aux[(long long)row * 1536 + col];       // + Wc1[d2][k]
          Cf[(long long)row * 768 + col] = v;
          Cbf[(long long)row * 768 + col] = f2bf(v);
        } else if constexpr (MODE == 1) {
          v += aux[row];                               // + bk[d1]
          if (mb[col] == 0) v = 0.0f;                  // zero masked key rows
          Cbf[(long long)b * cStr + (long long)row * ldc + col] = f2bf(v);
        } else if constexpr (MODE == 2 || MODE == 3) {
          Cbf[(long long)b * cStr + (long long)row * ldc + col] = f2bf(v);
        } else {
          Cf[(long long)b * cStr + (long long)row * ldc + col] = v * SCALE + aux[b * 768 + col];
        }
      }
}

// row[b][d2] = bc[d2] - 1e9*sum_{mask==0} Mt[d2][k] + SCALE*sum_d1 bq[d1]*Nt[b][d2][d1]
__global__ void k_row(const float* __restrict__ Mt, const unsigned short* __restrict__ Nt,
                      const int* __restrict__ mask, const float* __restrict__ bq,
                      const float* __restrict__ bc, float* __restrict__ row)
{
  int gw = blockIdx.x * 4 + (threadIdx.x >> 6);   // one wave per (b,d2)
  int lane = threadIdx.x & 63;
  int b = gw / 768;
  int d2 = gw - b * 768;
  if (b >= 8) return;
  const int* mb = mask + b * 768;
  const float* mrow = Mt + (long long)d2 * 768;
  const unsigned short* nrow = Nt + ((long long)b * 768 + d2) * 768;
  float sm = 0.f, sb = 0.f;
  for (int k = lane; k < 768; k += 64) {
    if (mb[k] == 0) sm += mrow[k];
    sb += bq[k] * bf2f(nrow[k]);
  }
  #pragma unroll
  for (int off = 32; off > 0; off >>= 1) {
    sm += __shfl_down(sm, off, 64);
    sb += __shfl_down(sb, off, 64);
  }
  if (lane == 0) row[gw] = bc[d2] - 1e9f * sm + SCALE * sb;
}

extern "C" void kernel_launch(void* const* d_in, const int* in_sizes, int n_in,
                              void* d_out, int out_size, void* d_ws, size_t ws_size,
                              hipStream_t stream)
{
  const float* query = (const float*)d_in[0];
  const float* key   = (const float*)d_in[1];
  const float* prev  = (const float*)d_in[3];
  const int*   mask  = (const int*)d_in[4];
  const float* Wq    = (const float*)d_in[5];
  const float* bq    = (const float*)d_in[6];
  const float* Wk    = (const float*)d_in[7];
  const float* bk    = (const float*)d_in[8];
  const float* Wc    = (const float*)d_in[11];
  const float* bc    = (const float*)d_in[12];
  float* out = (float*)d_out;

  char* p = (char*)d_ws;
  size_t off = 0;
  auto alloc = [&](size_t bytes) {
    char* r = p + off;
    off += (bytes + 255) & ~(size_t)255;
    return r;
  };
  unsigned short* query_bf = (unsigned short*)alloc(12582912ull * 2);
  unsigned short* key_bf   = (unsigned short*)alloc(4718592ull * 2);
  unsigned short* prev_bf  = (unsigned short*)alloc(589824ull * 2);
  unsigned short* Wk_bf    = (unsigned short*)alloc(589824ull * 2);
  unsigned short* Wc2_bf   = (unsigned short*)alloc(589824ull * 2);
  unsigned short* WqT_bf   = (unsigned short*)alloc(589824ull * 2);
  float*          Mt_f     = (float*)alloc(589824ull * 4);
  unsigned short* Mt_bf    = (unsigned short*)alloc(589824ull * 2);
  unsigned short* KzT_bf   = (unsigned short*)alloc(4718592ull * 2);
  unsigned short* Nt_bf    = (unsigned short*)alloc(4718592ull * 2);
  float*          rowv     = (float*)alloc(6144ull * 4);
  unsigned short* Pt_bf    = KzT_bf;   // KzT dead after G3 -> reuse buffer
  (void)ws_size; (void)in_sizes; (void)n_in; (void)out_size;

  // f32 -> bf16 staging (HBM-BW passes)
  k_cvt<<<dim3(12288), dim3(256), 0, stream>>>(query, query_bf, 3145728);
  k_cvt<<<dim3(4608),  dim3(256), 0, stream>>>(key, key_bf, 1179648);
  k_prep<<<dim3(1728), dim3(256), 0, stream>>>(Wk, prev, Wc, Wk_bf, prev_bf, Wc2_bf);
  k_transpose<<<dim3(12, 12), dim3(256), 0, stream>>>(Wq, WqT_bf);

  // G1: Mt[d2][k] = Wc1[d2][k] + sum_j Wc2[d2][j]*prev[k][j]
  gemm_nt<0, 64, 64><<<dim3(12, 12, 1), dim3(256), 0, stream>>>(
      Wc2_bf, 0ll, 768, prev_bf, 0ll, 768, Mt_f, Mt_bf, 0ll, 768, Wc, (const int*)nullptr);
  // G2: KzT[b][d1][k] = mask[b][k] ? (sum_j Wk[d1][j]*key[b][k][j] + bk[d1]) : 0
  gemm_nt<1, 64, 64><<<dim3(12, 12, 8), dim3(256), 0, stream>>>(
      Wk_bf, 0ll, 768, key_bf, 589824ll, 768, (float*)nullptr, KzT_bf, 589824ll, 768, bk, mask);
  // G3: Nt[b][d2][d1] = sum_k Mt[d2][k]*KzT[b][d1][k]
  gemm_nt<2, 64, 64><<<dim3(12, 12, 8), dim3(256), 0, stream>>>(
      Mt_bf, 0ll, 768, KzT_bf, 589824ll, 768, (float*)nullptr, Nt_bf, 589824ll, 768,
      (const float*)nullptr, (const int*)nullptr);
  // row constants (fp32 Mt + Nt)
  k_row<<<dim3(1536), dim3(256), 0, stream>>>(Mt_f, Nt_bf, mask, bq, bc, rowv);
  // G4: Pt[b][d2][d0] = sum_d1 Nt[b][d2][d1]*WqT[d0][d1]
  gemm_nt<3, 64, 64><<<dim3(12, 12, 8), dim3(256), 0, stream>>>(
      Nt_bf, 589824ll, 768, WqT_bf, 0ll, 768, (float*)nullptr, Pt_bf, 589824ll, 768,
      (const float*)nullptr, (const int*)nullptr);
  // G5: out[b][q][d2] = SCALE*sum_d0 query[b][q][d0]*Pt[b][d2][d0] + row[b][d2]
  gemm_nt<4, 128, 128><<<dim3(6, 16, 8), dim3(256), 0, stream>>>(
      query_bf, 1572864ll, 768, Pt_bf, 589824ll, 768, out, (unsigned short*)nullptr,
      1572864ll, 768, rowv, (const int*)nullptr);
}

// Round 7
// 123.427 us; speedup vs baseline: 1.1541x; 1.1541x over previous
//
#include <hip/hip_runtime.h>
#include <hip/hip_bf16.h>

// out[b] = SCALE*query[b]@P[b] + row[b]
//   M  = Wc1^T + prev@Wc2^T            (Mt = M^T, fp32+bf16)
//   Tt[b] = NT(Mt, keyzT[b])           (T = keyz^T@M; keyz = key rows zeroed by mask)
//   W2 = Wq^T@Wk,  u = Wq^T bk,  w3 = Wk^T bq
//   Pt[b] = NT(Tt[b], W2) + s1[b][d2]*u[d0]     (rank-1 bk-term folded in epilogue)
//   s1[b][d]  = sum_{mask=1} M[k][d],  sm0 = sum_{mask=0} M[k][d]
//   row[b][d] = bc[d] - 1e9*sm0[b][d] + SCALE*(w3@T[b] + (bq.bk)*s1[b][d])
//   G5: out = SCALE*NT(query_f32, Pt) + row     (query staged fp32, packed in-reg)
// NT GEMMs: bf16 MFMA 16x16x32, BK=64, global_load_lds(16B), rotation LDS
// swizzle (measured 0 conflicts), bijective XCD swizzle, round-5 proven
// single-buffer schedule (explicit dbuf regressed, r6).

typedef __attribute__((ext_vector_type(8))) short short8;
typedef __attribute__((ext_vector_type(4))) float f32x4;
typedef __attribute__((ext_vector_type(4))) unsigned int u32x4;

#define SCALE 0.03608439182435161f   /* 1/sqrt(768) */

__device__ inline unsigned short f2bf(float x) {
  unsigned int u = __builtin_bit_cast(unsigned int, x);
  u = (u + 0x7fffu + ((u >> 16) & 1u)) >> 16;   // RNE
  return (unsigned short)u;
}
__device__ inline float bf2f(unsigned short h) {
  return __builtin_bit_cast(float, ((unsigned int)h) << 16);
}
__device__ inline unsigned int pack_trunc(float hi, float lo) {
  // {bf16(lo) | bf16(hi)<<16} via one v_perm (truncation; data path only)
  return __builtin_amdgcn_perm(__builtin_bit_cast(unsigned int, hi),
                               __builtin_bit_cast(unsigned int, lo), 0x07060302u);
}

// ---------------- prep kernels ----------------
// region 0: prev cvt, region 1: Wc2 slice cvt
__global__ void k_prep(const float* __restrict__ prev, const float* __restrict__ Wc,
                       unsigned short* __restrict__ prev_bf,
                       unsigned short* __restrict__ Wc2_bf) {
  int g = blockIdx.x;
  int region = g / 576;
  int idx = (g - region * 576) * 256 + threadIdx.x;       // < 147456 float4-groups
  float4 v;
  unsigned short* dst;
  if (region == 0) { v = reinterpret_cast<const float4*>(prev)[idx]; dst = prev_bf; }
  else {
    int r = idx / 192, c4 = (idx - r * 192) * 4;
    v = *reinterpret_cast<const float4*>(Wc + (long long)r * 1536 + 768 + c4);
    dst = Wc2_bf;
  }
  reinterpret_cast<ushort4*>(dst)[idx] = make_ushort4(f2bf(v.x), f2bf(v.y), f2bf(v.z), f2bf(v.w));
}

// z=0: WqT = Wq^T;  z=1: WkT = Wk^T  (LDS-tiled, bf16 out)
__global__ void k_tposeW(const float* __restrict__ Wq, const float* __restrict__ Wk,
                         unsigned short* __restrict__ WqT, unsigned short* __restrict__ WkT) {
  __shared__ float t[64][65];
  const float* src = blockIdx.z ? Wk : Wq;
  unsigned short* dst = blockIdx.z ? WkT : WqT;
  int bx = blockIdx.x * 64, by = blockIdx.y * 64;
  int tx = threadIdx.x & 63, ty = threadIdx.x >> 6;
  #pragma unroll
  for (int i = 0; i < 64; i += 4)
    t[ty + i][tx] = src[(long long)(by + ty + i) * 768 + bx + tx];
  __syncthreads();
  #pragma unroll
  for (int i = 0; i < 64; i += 4)
    dst[(long long)(bx + ty + i) * 768 + by + tx] = f2bf(t[tx][ty + i]);
}

// keyzT[b][d1][k] = f2bf(mask[b][k] ? key[b][k][d1] : 0)
__global__ void k_cvtz(const float* __restrict__ key, const int* __restrict__ mask,
                       unsigned short* __restrict__ keyzT) {
  __shared__ float t[64][65];
  int b = blockIdx.z;
  const float* src = key + (long long)b * 589824;
  unsigned short* dst = keyzT + (long long)b * 589824;
  const int* mb = mask + b * 768;
  int bx = blockIdx.x * 64, by = blockIdx.y * 64;   // by+r = k, bx+c = d1
  int tx = threadIdx.x & 63, ty = threadIdx.x >> 6;
  #pragma unroll
  for (int i = 0; i < 64; i += 4) {
    float v = src[(long long)(by + ty + i) * 768 + bx + tx];
    t[ty + i][tx] = mb[by + ty + i] ? v : 0.0f;
  }
  __syncthreads();
  #pragma unroll
  for (int i = 0; i < 64; i += 4)
    dst[(long long)(bx + ty + i) * 768 + by + tx] = f2bf(t[tx][ty + i]);
}

// u[d0] = sum_j WqT[d0][j]*bk[j];  w3[d1] = sum_j WkT[d1][j]*bq[j]
__global__ void k_scalars(const unsigned short* __restrict__ WqT,
                          const unsigned short* __restrict__ WkT,
                          const float* __restrict__ bk, const float* __restrict__ bq,
                          float* __restrict__ u, float* __restrict__ w3) {
  int gw = blockIdx.x * 4 + (threadIdx.x >> 6);
  int lane = threadIdx.x & 63;
  if (gw >= 1536) return;
  const unsigned short* wrow = (gw < 768) ? (WqT + (long long)gw * 768)
                                          : (WkT + (long long)(gw - 768) * 768);
  const float* vec = (gw < 768) ? bk : bq;
  float s = 0.f;
  for (int j = lane; j < 768; j += 64) s += bf2f(wrow[j]) * vec[j];
  #pragma unroll
  for (int off = 32; off > 0; off >>= 1) s += __shfl_down(s, off, 64);
  if (lane == 0) { if (gw < 768) u[gw] = s; else w3[gw - 768] = s; }
}

// s1[b][d2]=sum_{mask=1}Mt[d2][k]; sm0[b][d2]=sum_{mask=0}Mt[d2][k]  (fp32)
__global__ void k_scol(const float* __restrict__ Mt, const int* __restrict__ mask,
                       float* __restrict__ s1, float* __restrict__ sm0) {
  int gw = blockIdx.x * 4 + (threadIdx.x >> 6);
  int lane = threadIdx.x & 63;
  int b = gw / 768, d2 = gw - b * 768;
  if (b >= 8) return;
  const int* mb = mask + b * 768;
  const float* mrow = Mt + (long long)d2 * 768;
  float a1 = 0.f, a0 = 0.f;
  for (int k = lane; k < 768; k += 64) {
    float v = mrow[k];
    if (mb[k]) a1 += v; else a0 += v;
  }
  #pragma unroll
  for (int off = 32; off > 0; off >>= 1) {
    a1 += __shfl_down(a1, off, 64);
    a0 += __shfl_down(a0, off, 64);
  }
  if (lane == 0) { s1[gw] = a1; sm0[gw] = a0; }
}

// row[b][d2] = bc - 1e9*sm0 + SCALE*(sum_d1 Tt[b][d2][d1]*w3[d1] + (bq.bk)*s1)
__global__ void k_row(const unsigned short* __restrict__ Tt, const float* __restrict__ w3,
                      const float* __restrict__ s1, const float* __restrict__ sm0,
                      const float* __restrict__ bq, const float* __restrict__ bk,
                      const float* __restrict__ bc, float* __restrict__ row) {
  int gw = blockIdx.x * 4 + (threadIdx.x >> 6);
  int lane = threadIdx.x & 63;
  int b = gw / 768, d2 = gw - b * 768;
  if (b >= 8) return;
  const unsigned short* trow = Tt + ((long long)b * 768 + d2) * 768;
  float st = 0.f, sbb = 0.f;
  for (int j = lane; j < 768; j += 64) {
    st += bf2f(trow[j]) * w3[j];
    sbb += bq[j] * bk[j];
  }
  #pragma unroll
  for (int off = 32; off > 0; off >>= 1) {
    st += __shfl_down(st, off, 64);
    sbb += __shfl_down(sbb, off, 64);
  }
  if (lane == 0)
    row[gw] = bc[d2] - 1e9f * sm0[gw] + SCALE * (st + sbb * s1[gw]);
}

// ---------------- NT GEMM: C[m][n] = sum_k A[m][k]*B[n][k], K=768, BK=64 ----------
// MODE 0: Mt fp32+bf16 = acc + Wc1[m][n] (aux=Wc ld1536)
// MODE 2: bf16 = acc
// MODE 4: out fp32 = SCALE*acc + aux[b*768+n]              (row add)
// MODE 5: bf16 = acc + aux[b*768+m]*aux2[n]                (rank-1 fold)
// AF32: A operand is raw fp32 (16-granule rows, rotation &15, perm-trunc packs)
template <int MODE, int BM, int BN, int AF32>
__global__ __launch_bounds__(256) void gemm_nt(
    const void* __restrict__ A, long long aStr, int lda,
    const unsigned short* __restrict__ B, long long bStr, int ldb,
    float* __restrict__ Cf, unsigned short* __restrict__ Cbf,
    long long cStr, int ldc,
    const float* __restrict__ aux, const float* __restrict__ aux2)
{
  constexpr int BK = 64;
  constexpr int EA = AF32 ? 4 : 2;
  constexpr int AGR = BK * EA / 16;        // granules per A row: 16 (f32) / 8 (bf16)
  constexpr int MI = BM / 32, NJ = BN / 32;
  constexpr int AGT = BM * AGR / 256, BGT = BN * 8 / 256;
  constexpr int ARB = BK * EA;             // A row bytes
  __shared__ __align__(16) char As[BM * BK * EA];
  __shared__ __align__(16) char Bs[BN * BK * 2];

  // bijective XCD swizzle (m204)
  const int gx = gridDim.x, gy = gridDim.y;
  const int nwg = gx * gy * (int)gridDim.z;
  int lin = blockIdx.x + gx * (blockIdx.y + gy * blockIdx.z);
  int qq = nwg >> 3, rr = nwg & 7, xcd = lin & 7, loc = lin >> 3;
  int swz = (xcd < rr ? xcd * (qq + 1) : rr * (qq + 1) + (xcd - rr) * qq) + loc;
  int bz = swz / (gx * gy);
  int rem = swz - bz * gx * gy;
  int by = rem / gx, bx = rem - by * gx;

  const int b = bz;
  const char* Ab = (const char*)A + (long long)b * aStr * EA;
  const unsigned short* Bb = B + (long long)b * bStr;
  const int m0 = by * BM, n0 = bx * BN;

  const int tid = threadIdx.x;
  const int w = tid >> 6, lane = tid & 63;
  const int wr = w >> 1, wc = w & 1;       // 2x2 waves
  const int fr = lane & 15, fq = lane >> 4;

  f32x4 acc[MI][NJ] = {};

  for (int kt = 0; kt < 768; kt += BK) {
    __syncthreads();
    #pragma unroll
    for (int t = 0; t < AGT; ++t) {
      int g = t * 256 + tid;
      int row = g / AGR, s = g & (AGR - 1);
      int sg = (s - row) & (AGR - 1);                 // inverse-rotation source
      long long boff = ((long long)(m0 + row) * lda + kt) * EA + sg * 16;
      __builtin_amdgcn_global_load_lds(
          (const __attribute__((address_space(1))) void*)(Ab + boff),
          (__attribute__((address_space(3))) void*)(As + g * 16), 16, 0, 0);
    }
    #pragma unroll
    for (int t = 0; t < BGT; ++t) {
      int g = t * 256 + tid;
      int row = g >> 3, s = g & 7;
      int sg = (s - row) & 7;
      const unsigned short* gb = Bb + (long long)(n0 + row) * ldb + kt + sg * 8;
      __builtin_amdgcn_global_load_lds(
          (const __attribute__((address_space(1))) void*)gb,
          (__attribute__((address_space(3))) void*)(Bs + g * 16), 16, 0, 0);
    }
    __syncthreads();

    #pragma unroll
    for (int kk = 0; kk < 2; ++kk) {
      short8 af[MI], bfr[NJ];
      #pragma unroll
      for (int i = 0; i < MI; ++i) {
        int r = wr * (BM / 2) + i * 16 + fr;
        if constexpr (AF32) {
          const f32x4* base = (const f32x4*)(As + r * ARB);
          int gidx = kk * 8 + fq * 2;
          f32x4 x = base[(gidx + r) & 15];
          f32x4 y = base[(gidx + 1 + r) & 15];
          unsigned int p0 = pack_trunc(x[1], x[0]), p1 = pack_trunc(x[3], x[2]);
          unsigned int p2 = pack_trunc(y[1], y[0]), p3 = pack_trunc(y[3], y[2]);
          u32x4 u4 = {p0, p1, p2, p3};
          af[i] = __builtin_bit_cast(short8, u4);
        } else {
          int sgi = ((kk * 4 + fq) + r) & 7;          // rotation-swizzled granule
          af[i] = *reinterpret_cast<const short8*>(As + r * 128 + sgi * 16);
        }
      }
      #pragma unroll
      for (int j = 0; j < NJ; ++j) {
        int r = wc * (BN / 2) + j * 16 + fr;
        int sgj = ((kk * 4 + fq) + r) & 7;
        bfr[j] = *reinterpret_cast<const short8*>(Bs + r * 128 + sgj * 16);
      }
      #pragma unroll
      for (int i = 0; i < MI; ++i)
        #pragma unroll
        for (int j = 0; j < NJ; ++j)
          acc[i][j] = __builtin_amdgcn_mfma_f32_16x16x32_bf16(af[i], bfr[j], acc[i][j], 0, 0, 0);
    }
  }

  #pragma unroll
  for (int i = 0; i < MI; ++i)
    #pragma unroll
    for (int j = 0; j < NJ; ++j)
      #pragma unroll
      for (int r = 0; r < 4; ++r) {
        int row = m0 + wr * (BM / 2) + i * 16 + fq * 4 + r;  // C/D: col=lane&15, row=(lane>>4)*4+r
        int col = n0 + wc * (BN / 2) + j * 16 + fr;
        float v = acc[i][j][r];
        if constexpr (MODE == 0) {
          v += aux[(long long)row * 1536 + col];       // + Wc1[d2][k]
          Cf[(long long)row * 768 + col] = v;
          Cbf[(long long)row * 768 + col] = f2bf(v);
        } else if constexpr (MODE == 2) {
          Cbf[(long long)b * cStr + (long long)row * ldc + col] = f2bf(v);
        } else if constexpr (MODE == 5) {
          v += aux[b * 768 + row] * aux2[col];         // + s1[b][d2]*u[d0]
          Cbf[(long long)b * cStr + (long long)row * ldc + col] = f2bf(v);
        } else {
          Cf[(long long)b * cStr + (long long)row * ldc + col] = v * SCALE + aux[b * 768 + col];
        }
      }
}

extern "C" void kernel_launch(void* const* d_in, const int* in_sizes, int n_in,
                              void* d_out, int out_size, void* d_ws, size_t ws_size,
                              hipStream_t stream)
{
  const float* query = (const float*)d_in[0];
  const float* key   = (const float*)d_in[1];
  const float* prev  = (const float*)d_in[3];
  const int*   mask  = (const int*)d_in[4];
  const float* Wq    = (const float*)d_in[5];
  const float* bq    = (const float*)d_in[6];
  const float* Wk    = (const float*)d_in[7];
  const float* bk    = (const float*)d_in[8];
  const float* Wc    = (const float*)d_in[11];
  const float* bc    = (const float*)d_in[12];
  float* out = (float*)d_out;

  char* p = (char*)d_ws;
  size_t off = 0;
  auto alloc = [&](size_t bytes) {
    char* r = p + off;
    off += (bytes + 255) & ~(size_t)255;
    return r;
  };
  unsigned short* keyzT_bf = (unsigned short*)alloc(4718592ull * 2);
  unsigned short* WqT_bf   = (unsigned short*)alloc(589824ull * 2);
  unsigned short* WkT_bf   = (unsigned short*)alloc(589824ull * 2);
  unsigned short* prev_bf  = (unsigned short*)alloc(589824ull * 2);
  unsigned short* Wc2_bf   = (unsigned short*)alloc(589824ull * 2);
  float*          Mt_f     = (float*)alloc(589824ull * 4);
  unsigned short* Mt_bf    = (unsigned short*)alloc(589824ull * 2);
  unsigned short* W2_bf    = (unsigned short*)alloc(589824ull * 2);
  unsigned short* Tt_bf    = (unsigned short*)alloc(4718592ull * 2);
  unsigned short* Pt_bf    = (unsigned short*)alloc(4718592ull * 2);
  float*          s1f      = (float*)alloc(6144ull * 4);
  float*          sm0f     = (float*)alloc(6144ull * 4);
  float*          uv       = (float*)alloc(768ull * 4);
  float*          w3v      = (float*)alloc(768ull * 4);
  float*          rowv     = (float*)alloc(6144ull * 4);
  (void)ws_size; (void)in_sizes; (void)n_in; (void)out_size;

  // prep
  k_tposeW<<<dim3(12, 12, 2), dim3(256), 0, stream>>>(Wq, Wk, WqT_bf, WkT_bf);
  k_prep<<<dim3(1152), dim3(256), 0, stream>>>(prev, Wc, prev_bf, Wc2_bf);
  k_cvtz<<<dim3(12, 12, 8), dim3(256), 0, stream>>>(key, mask, keyzT_bf);

  // G1: Mt = NT(Wc2, prev) + Wc1
  gemm_nt<0, 64, 64, 0><<<dim3(12, 12, 1), dim3(256), 0, stream>>>(
      (const void*)Wc2_bf, 0ll, 768, prev_bf, 0ll, 768, Mt_f, Mt_bf, 0ll, 768,
      Wc, (const float*)nullptr);
  // W2 = NT(WqT, WkT)
  gemm_nt<2, 64, 64, 0><<<dim3(12, 12, 1), dim3(256), 0, stream>>>(
      (const void*)WqT_bf, 0ll, 768, WkT_bf, 0ll, 768, (float*)nullptr, W2_bf, 0ll, 768,
      (const float*)nullptr, (const float*)nullptr);
  // u, w3
  k_scalars<<<dim3(384), dim3(256), 0, stream>>>(WqT_bf, WkT_bf, bk, bq, uv, w3v);
  // s1 / sm0 from fp32 Mt
  k_scol<<<dim3(1536), dim3(256), 0, stream>>>(Mt_f, mask, s1f, sm0f);
  // G3': Tt[b] = NT(Mt, keyzT[b])
  gemm_nt<2, 64, 64, 0><<<dim3(12, 12, 8), dim3(256), 0, stream>>>(
      (const void*)Mt_bf, 0ll, 768, keyzT_bf, 589824ll, 768, (float*)nullptr, Tt_bf,
      589824ll, 768, (const float*)nullptr, (const float*)nullptr);
  // G4': Pt[b] = NT(Tt[b], W2) + s1[b][m]*u[n]
  gemm_nt<5, 64, 64, 0><<<dim3(12, 12, 8), dim3(256), 0, stream>>>(
      (const void*)Tt_bf, 589824ll, 768, W2_bf, 0ll, 768, (float*)nullptr, Pt_bf,
      589824ll, 768, s1f, uv);
  // row constants
  k_row<<<dim3(1536), dim3(256), 0, stream>>>(Tt_bf, w3v, s1f, sm0f, bq, bk, bc, rowv);
  // G5: out = SCALE*NT(query_f32, Pt) + row
  gemm_nt<4, 128, 128, 1><<<dim3(6, 16, 8), dim3(256), 0, stream>>>(
      (const void*)query, 1572864ll, 768, Pt_bf, 589824ll, 768, out,
      (unsigned short*)nullptr, 1572864ll, 768, rowv, (const float*)nullptr);
}